// Round 13
// baseline (86.567 us; speedup 1.0000x reference)
//
#include <hip/hip_runtime.h>
#include <hip/hip_bf16.h>
#include <stdint.h>

// Problem constants: B=8, T=2048, C=1024, H=64. Single-head causal attention.
#define Bn 8
#define Tn 2048
#define Cn 1024
#define Hn 64

typedef __attribute__((ext_vector_type(8))) short bf16x8;  // 8 bf16 (MFMA K=32 A/B frag)
typedef __attribute__((ext_vector_type(4))) short bf16x4;  // 4 bf16 (MFMA K=16 A/B frag)
typedef __attribute__((ext_vector_type(4))) float f32x4;   // MFMA C/D frag

// __has_builtin for amdgcn builtins is false in the HOST pass; device-only check.
#if defined(__HIP_DEVICE_COMPILE__) && !__has_builtin(__builtin_amdgcn_mfma_f32_16x16x16bf16_1k)
#error "mfma_f32_16x16x16bf16_1k required on gfx950"
#endif
#define MFMA16(a, b, c) __builtin_amdgcn_mfma_f32_16x16x16bf16_1k(a, b, c, 0, 0, 0)
#define MFMA32(a, b, c) __builtin_amdgcn_mfma_f32_16x16x32_bf16(a, b, c, 0, 0, 0)

__device__ __forceinline__ unsigned short f2bf(float f) {
  union { float f; unsigned int u; } v; v.f = f;
  unsigned int u = v.u;
  u = u + 0x7fffu + ((u >> 16) & 1u);   // round-nearest-even
  return (unsigned short)(u >> 16);
}

// async global(16B/lane) -> LDS (wave-uniform dest base + lane*16)
__device__ __forceinline__ void gload16(const void* g, void* l) {
  __builtin_amdgcn_global_load_lds(
      (const __attribute__((address_space(1))) unsigned int*)g,
      (__attribute__((address_space(3))) unsigned int*)l, 16, 0, 0);
}

// ---------------------------------------------------------------------------
// k_prep: Wt[m][h][c] = W_m[c][h] as bf16.  grid=192 (m*64+h), block=256.
// ---------------------------------------------------------------------------
__global__ __launch_bounds__(256) void k_prep(const float* __restrict__ Wq,
                                              const float* __restrict__ Wk,
                                              const float* __restrict__ Wv,
                                              unsigned short* __restrict__ Wt) {
  const int m = blockIdx.x >> 6;
  const int h = blockIdx.x & 63;
  const float* W = (m == 0) ? Wq : (m == 1) ? Wk : Wv;
  const int tid = threadIdx.x;
  unsigned short* dst = Wt + ((size_t)(m * 64 + h)) * 1024;
#pragma unroll
  for (int j = 0; j < 4; ++j) {
    int c = j * 256 + tid;
    dst[c] = f2bf(W[(size_t)c * 64 + h]);
  }
}

// ---------------------------------------------------------------------------
// k_qkv REGISTER-DIRECT: C[16384x192] = x * W, NO K-loop LDS, NO K-loop
// barriers. R8/R9/R11/R12 all landed at 37-39us regardless of staging
// structure: the invariant was the barrier-serialized global->LDS->MFMA
// round-trip (ds aliasing + syncthreads pins instruction order; compiler
// cannot overlap). Here both operands are loaded directly from global as
// MFMA fragments: A = 8 fp32 of own x row (16 rows x 64B contiguous per
// instr, coalesced; cvt->bf16 in-reg), B = bf16x8 from L2-resident Wt
// (384KB). Fully-unrolled free-running K-loop -> compiler prefetches deep
// (256-VGPR budget via (256,2)). Block = 4 waves x (32 rows x 48 cols),
// col-split so all waves share the same x rows via L1/L2. Grid 512, 2 blk/CU.
// One barrier total (epilogue transpose).
// ---------------------------------------------------------------------------
__global__ __launch_bounds__(256, 2) void k_qkv(const float* __restrict__ x,
                                                const unsigned short* __restrict__ Wt,
                                                unsigned short* __restrict__ Q,
                                                unsigned short* __restrict__ K,
                                                unsigned short* __restrict__ Vt) {
  __shared__ __align__(16) unsigned short os[32][200];  // epilogue only

  const int tid = threadIdx.x;
  const int lane = tid & 63;
  const int wid = tid >> 6;           // col group: 48*wid .. 48*wid+47
  const int l15 = lane & 15, g = lane >> 4;
  const int r0 = blockIdx.x * 32;

  f32x4 acc[2][3];
#pragma unroll
  for (int mf = 0; mf < 2; ++mf)
#pragma unroll
    for (int nf = 0; nf < 3; ++nf)
#pragma unroll
      for (int r = 0; r < 4; ++r) acc[mf][nf][r] = 0.f;

  // per-lane base pointers (A rows and B rows fixed across K)
  const float* xr0 = x + (size_t)(r0 + l15) * 1024 + g * 8;
  const float* xr1 = x + (size_t)(r0 + 16 + l15) * 1024 + g * 8;
  const unsigned short* wr0 = Wt + (size_t)(wid * 48 + l15) * 1024 + g * 8;
  const unsigned short* wr1 = wr0 + 16 * 1024;
  const unsigned short* wr2 = wr0 + 32 * 1024;

#pragma unroll
  for (int ks = 0; ks < 32; ++ks) {
    const int k0 = ks * 32;
    // A-frags: 8 fp32 -> bf16x8, two row groups
    float4 a0l = *(const float4*)(xr0 + k0);
    float4 a0h = *(const float4*)(xr0 + k0 + 4);
    float4 a1l = *(const float4*)(xr1 + k0);
    float4 a1h = *(const float4*)(xr1 + k0 + 4);
    bf16x8 a0, a1;
    a0[0] = (short)f2bf(a0l.x); a0[1] = (short)f2bf(a0l.y);
    a0[2] = (short)f2bf(a0l.z); a0[3] = (short)f2bf(a0l.w);
    a0[4] = (short)f2bf(a0h.x); a0[5] = (short)f2bf(a0h.y);
    a0[6] = (short)f2bf(a0h.z); a0[7] = (short)f2bf(a0h.w);
    a1[0] = (short)f2bf(a1l.x); a1[1] = (short)f2bf(a1l.y);
    a1[2] = (short)f2bf(a1l.z); a1[3] = (short)f2bf(a1l.w);
    a1[4] = (short)f2bf(a1h.x); a1[5] = (short)f2bf(a1h.y);
    a1[6] = (short)f2bf(a1h.z); a1[7] = (short)f2bf(a1h.w);
    // B-frags straight from L2-resident Wt
    bf16x8 b0 = *(const bf16x8*)(wr0 + k0);
    bf16x8 b1 = *(const bf16x8*)(wr1 + k0);
    bf16x8 b2 = *(const bf16x8*)(wr2 + k0);
    acc[0][0] = MFMA32(a0, b0, acc[0][0]);
    acc[0][1] = MFMA32(a0, b1, acc[0][1]);
    acc[0][2] = MFMA32(a0, b2, acc[0][2]);
    acc[1][0] = MFMA32(a1, b0, acc[1][0]);
    acc[1][1] = MFMA32(a1, b1, acc[1][1]);
    acc[1][2] = MFMA32(a1, b2, acc[1][2]);
  }

  // epilogue: acc -> os (bf16). D layout: col = l15, row = 4g+r.
#pragma unroll
  for (int mf = 0; mf < 2; ++mf)
#pragma unroll
    for (int nf = 0; nf < 3; ++nf)
#pragma unroll
      for (int r = 0; r < 4; ++r)
        os[mf * 16 + 4 * g + r][wid * 48 + nf * 16 + l15] = f2bf(acc[mf][nf][r]);
  __syncthreads();

  const int b = r0 >> 11;
  const int t0 = r0 & 2047;
  // Q, K: 32 rows x 8 uint4-chunks = 256 each
  {
    int row = tid >> 3, ch = tid & 7;
    *(uint4*)(Q + (size_t)(r0 + row) * 64 + ch * 8) = *(const uint4*)&os[row][ch * 8];
    *(uint4*)(K + (size_t)(r0 + row) * 64 + ch * 8) = *(const uint4*)&os[row][64 + ch * 8];
  }
  // Vt transpose: 64 h x 32 t; each thread 8 t-values (16B store)
  {
    int h = tid >> 2, tc = (tid & 3) * 8;
    unsigned short tmp[8];
#pragma unroll
    for (int r = 0; r < 8; ++r) tmp[r] = os[tc + r][128 + h];
    *(uint4*)(Vt + ((size_t)b * 64 + h) * 2048 + t0 + tc) = *(const uint4*)tmp;
  }
}

// ---------------------------------------------------------------------------
// k_attn_coop: block-cooperative flash attention. UNCHANGED from R7-R12
// (inferred ~11us: (256,3), XCD-bijective swizzle, gload_lds dbuf staging).
// ---------------------------------------------------------------------------
__global__ __launch_bounds__(256, 3) void k_attn_coop(const unsigned short* __restrict__ Q,
                                                      const unsigned short* __restrict__ K,
                                                      const unsigned short* __restrict__ Vt,
                                                      float* __restrict__ out,
                                                      float* __restrict__ po,
                                                      float* __restrict__ pml) {
  __shared__ __align__(16) unsigned short lds[2][8192];  // [buf][K 4096sh | V 4096sh]

  const int tid = threadIdx.x;
  const int lane = tid & 63;
  const int l15 = lane & 15, g = lane >> 4;
  const int wid = __builtin_amdgcn_readfirstlane(tid >> 6);

  // ---- task decode with XCD swizzle (1152 = 8 XCD x 144 tasks/batch) ----
  const int raw = blockIdx.x;
  const int bi = (raw & 7) * 144 + (raw >> 3);
  const int b = bi / 144;
  const int id = bi - b * 144;
  int gq = 0;
#pragma unroll
  for (int t = 1; t < 8; ++t)
    if (id >= 2 * t * (t + 1)) gq = t;
  const int rem = id - 2 * gq * (gq + 1);
  const int ql = rem / (gq + 1);
  const int s = rem - ql * (gq + 1);
  const int qt = 4 * gq + ql;          // 64-row q-tile 0..31
  const int qblk = qt * 64;
  const int klo = 256 * s;
  const int khi = min(klo + 256, qblk + 64);
  const int nt = (khi - klo + 63) >> 6;
  const int q0w = qblk + wid * 16;     // this wave's q rows

  const unsigned short* Qb = Q + (size_t)b * Tn * Hn;
  const unsigned short* Kb = K + (size_t)b * Tn * Hn;
  const unsigned short* Vb = Vt + (size_t)b * Hn * Tn;

  // Q as B-operand: lane l15 = q row, k = 8g+j
  bf16x8 bq0 = *(const bf16x8*)(Qb + (size_t)(q0w + l15) * 64 + g * 8);
  bf16x8 bq1 = *(const bf16x8*)(Qb + (size_t)(q0w + l15) * 64 + 32 + g * 8);

  f32x4 o[4];
#pragma unroll
  for (int hf = 0; hf < 4; ++hf)
#pragma unroll
    for (int r = 0; r < 4; ++r) o[hf][r] = 0.f;
  float m = -1e30f, lsum = 0.f;
  const float sc = 0.03125f * 1.44269504088896f;  // C^-0.5 * log2(e)

  // stage one 64-key tile: K[64key][64d] + V[64h][64key], swizzled granules.
  auto stage = [&](int buf, int k0) {
    unsigned short* tb = &lds[buf][0];
#pragma unroll
    for (int j = 0; j < 4; ++j) {
      const int p = wid * 256 + j * 64 + lane;
      const unsigned short* src;
      if (wid < 2) {                       // K: rows = keys
        const int row = p >> 3, c = p & 7;
        src = Kb + (size_t)(k0 + row) * 64 + ((c ^ (row & 7)) * 8);
      } else {                             // V: rows = h
        const int q = p - 512;
        const int h = q >> 3, c = q & 7;
        src = Vb + (size_t)h * Tn + k0 + ((c ^ (h & 7)) * 8);
      }
      gload16(src, tb + wid * 2048 + j * 512);
    }
  };

  stage(0, klo);
  __syncthreads();

  for (int t = 0; t < nt; ++t) {
    const int cur = t & 1;
    const int k0 = klo + t * 64;
    if (t + 1 < nt) stage(cur ^ 1, klo + (t + 1) * 64);

    const unsigned short* kt = &lds[cur][0];
    const unsigned short* vt = &lds[cur][4096];

    // S^T: lane l15 = q, reg (kc, 4g+r) = key
    f32x4 sacc[4];
#pragma unroll
    for (int kc = 0; kc < 4; ++kc) {
      const int row = kc * 16 + l15;
      const int sw = row & 7;
      bf16x8 ka = *(const bf16x8*)&kt[row * 64 + ((g ^ sw) * 8)];
      bf16x8 kb2 = *(const bf16x8*)&kt[row * 64 + (((4 + g) ^ sw) * 8)];
#pragma unroll
      for (int r = 0; r < 4; ++r) sacc[kc][r] = 0.f;
      sacc[kc] = MFMA32(ka, bq0, sacc[kc]);
      sacc[kc] = MFMA32(kb2, bq1, sacc[kc]);
    }
    // scale + causal mask (key <= q); boundary tiles only (wave-uniform)
    float sv[4][4];
    if (k0 + 63 > q0w) {
      const int q = q0w + l15;
#pragma unroll
      for (int kc = 0; kc < 4; ++kc)
#pragma unroll
        for (int r = 0; r < 4; ++r) {
          int key = k0 + kc * 16 + 4 * g + r;
          sv[kc][r] = (key <= q) ? sacc[kc][r] * sc : -1e30f;
        }
    } else {
#pragma unroll
      for (int kc = 0; kc < 4; ++kc)
#pragma unroll
        for (int r = 0; r < 4; ++r) sv[kc][r] = sacc[kc][r] * sc;
    }
    // defer-max: lane-local max suffices for the trigger test
    float pm = sv[0][0];
#pragma unroll
    for (int kc = 0; kc < 4; ++kc)
#pragma unroll
      for (int r = 0; r < 4; ++r) pm = fmaxf(pm, sv[kc][r]);
    if (__any(pm > m + 8.f)) {
      pm = fmaxf(pm, __shfl_xor(pm, 16));
      pm = fmaxf(pm, __shfl_xor(pm, 32));
      float mn = fmaxf(m, pm);
      float alpha = exp2f(m - mn);
      lsum *= alpha;
      float an[4];
#pragma unroll
      for (int r = 0; r < 4; ++r) an[r] = __shfl(alpha, 4 * g + r);
#pragma unroll
      for (int hf = 0; hf < 4; ++hf)
#pragma unroll
        for (int r = 0; r < 4; ++r) o[hf][r] *= an[r];
      m = mn;
    }
    float ts = 0.f;
#pragma unroll
    for (int kc = 0; kc < 4; ++kc)
#pragma unroll
      for (int r = 0; r < 4; ++r) { sv[kc][r] = exp2f(sv[kc][r] - m); ts += sv[kc][r]; }
    ts += __shfl_xor(ts, 16);
    ts += __shfl_xor(ts, 32);
    lsum += ts;
    // P in K=16 A-operand layout: lane l15 = q, k-local = 4g+r
    bf16x4 pa[4];
#pragma unroll
    for (int kc = 0; kc < 4; ++kc) {
      pa[kc][0] = (short)f2bf(sv[kc][0]); pa[kc][1] = (short)f2bf(sv[kc][1]);
      pa[kc][2] = (short)f2bf(sv[kc][2]); pa[kc][3] = (short)f2bf(sv[kc][3]);
    }
    // V frags from LDS: B-operand lane l15 = h col, k-local = 4g+r
    bf16x4 vf[4][4];
#pragma unroll
    for (int hf = 0; hf < 4; ++hf) {
      const int h = hf * 16 + l15, hs = h & 7;
#pragma unroll
      for (int kc = 0; kc < 4; ++kc) {
        const int gran = (kc * 2 + (g >> 1)) ^ hs;
        vf[hf][kc] = *(const bf16x4*)&vt[h * 64 + gran * 8 + (g & 1) * 4];
      }
    }
#pragma unroll
    for (int hf = 0; hf < 4; ++hf)
#pragma unroll
      for (int kc = 0; kc < 4; ++kc)
        o[hf] = MFMA16(pa[kc], vf[hf][kc], o[hf]);

    __syncthreads();   // drains stage vmcnt + all waves done reading buf
  }

  if (qt >= 4) {
    // packed partial: slot = task id - 4 within batch
    const int slot = b * 140 + id - 4;
    float* pob = po + (size_t)slot * 4096;
#pragma unroll
    for (int hf = 0; hf < 4; ++hf)
#pragma unroll
      for (int r = 0; r < 4; ++r)
        pob[(16 * wid + 4 * g + r) * 64 + hf * 16 + l15] = o[hf][r];
    if (lane < 16) {
      pml[(size_t)slot * 128 + 16 * wid + l15] = m;
      pml[(size_t)slot * 128 + 64 + 16 * wid + l15] = lsum;
    }
  } else {
    const float il = 1.f / lsum;
    float iln[4];
#pragma unroll
    for (int r = 0; r < 4; ++r) iln[r] = __shfl(il, 4 * g + r);
    float* ob = out + ((size_t)b * Tn + q0w) * 64;
#pragma unroll
    for (int hf = 0; hf < 4; ++hf)
#pragma unroll
      for (int r = 0; r < 4; ++r)
        ob[(size_t)(4 * g + r) * 64 + hf * 16 + l15] = o[hf][r] * iln[r];
  }
}

// ---------------------------------------------------------------------------
// k_comb: merge 2..8 segments per (b, qt 4..31). grid=(28,8), block=256.
// ---------------------------------------------------------------------------
__global__ __launch_bounds__(256) void k_comb(const float* __restrict__ po,
                                              const float* __restrict__ pml,
                                              float* __restrict__ out) {
  const int qt = 4 + blockIdx.x;
  const int b = blockIdx.y;
  const int gq = qt >> 2, ql = qt & 3;
  const int nseg = gq + 1;
  const int base = b * 140 + 2 * gq * (gq + 1) + ql * (gq + 1) - 4;
  const int r = threadIdx.x >> 2;
  const int cg = threadIdx.x & 3;

  float mv[8], lv[8], M = -1e30f;
#pragma unroll
  for (int s = 0; s < 8; ++s)
    if (s < nseg) {
      mv[s] = pml[(size_t)(base + s) * 128 + r];
      lv[s] = pml[(size_t)(base + s) * 128 + 64 + r];
      M = fmaxf(M, mv[s]);
    }
  float w[8], L = 0.f;
#pragma unroll
  for (int s = 0; s < 8; ++s)
    if (s < nseg) { w[s] = exp2f(mv[s] - M); L += w[s] * lv[s]; }

  float acc[16];
#pragma unroll
  for (int c = 0; c < 16; ++c) acc[c] = 0.f;
#pragma unroll
  for (int s = 0; s < 8; ++s)
    if (s < nseg) {
      const float* pb = po + (size_t)(base + s) * 4096 + r * 64 + cg * 16;
#pragma unroll
      for (int j = 0; j < 4; ++j) {
        float4 v = *(const float4*)(pb + 4 * j);
        acc[4 * j + 0] += w[s] * v.x; acc[4 * j + 1] += w[s] * v.y;
        acc[4 * j + 2] += w[s] * v.z; acc[4 * j + 3] += w[s] * v.w;
      }
    }
  const float invL = 1.f / L;
  float* ob = out + ((size_t)b * Tn + qt * 64 + r) * 64 + cg * 16;
#pragma unroll
  for (int j = 0; j < 4; ++j) {
    float4 v;
    v.x = acc[4 * j + 0] * invL; v.y = acc[4 * j + 1] * invL;
    v.z = acc[4 * j + 2] * invL; v.w = acc[4 * j + 3] * invL;
    *(float4*)(ob + 4 * j) = v;
  }
}

// ---------------------------------------------------------------------------
// k_attn_wave: per-wave fallback (full key range), tiny workspace only.
// ---------------------------------------------------------------------------
__global__ __launch_bounds__(256, 2) void k_attn_wave(const unsigned short* __restrict__ Q,
                                                      const unsigned short* __restrict__ K,
                                                      const unsigned short* __restrict__ Vt,
                                                      float* __restrict__ out) {
  const int tid = threadIdx.x;
  const int lane = tid & 63;
  const int l15 = lane & 15, g = lane >> 4;
  const int wid = tid >> 6;
  const int task = blockIdx.x * 4 + wid;
  const int b = task >> 7, qt = task & 127;
  const int q0 = qt * 16;
  const int nt = (q0 + 16 + 63) >> 6;

  const unsigned short* Qb = Q + (size_t)b * Tn * Hn;
  const unsigned short* Kb = K + (size_t)b * Tn * Hn;
  const unsigned short* Vb = Vt + (size_t)b * Hn * Tn;

  bf16x8 bq0 = *(const bf16x8*)(Qb + (size_t)(q0 + l15) * 64 + g * 8);
  bf16x8 bq1 = *(const bf16x8*)(Qb + (size_t)(q0 + l15) * 64 + 32 + g * 8);

  f32x4 o[4];
#pragma unroll
  for (int hf = 0; hf < 4; ++hf)
#pragma unroll
    for (int r = 0; r < 4; ++r) o[hf][r] = 0.f;
  float m = -1e30f, lsum = 0.f;
  const float sc = 0.03125f * 1.44269504088896f;

  for (int t = 0; t < nt; ++t) {
    const int k0 = t * 64;
    bf16x4 vf[4][4];
#pragma unroll
    for (int hf = 0; hf < 4; ++hf) {
      const unsigned short* vrow = Vb + (size_t)(hf * 16 + l15) * Tn + k0 + 4 * g;
#pragma unroll
      for (int kc = 0; kc < 4; ++kc) vf[hf][kc] = *(const bf16x4*)(vrow + kc * 16);
    }
    f32x4 sacc[4];
#pragma unroll
    for (int kc = 0; kc < 4; ++kc) {
      const unsigned short* kp = Kb + (size_t)(k0 + kc * 16 + l15) * 64 + g * 8;
      bf16x8 ka = *(const bf16x8*)kp;
      bf16x8 kb2 = *(const bf16x8*)(kp + 32);
#pragma unroll
      for (int r = 0; r < 4; ++r) sacc[kc][r] = 0.f;
      sacc[kc] = MFMA32(ka, bq0, sacc[kc]);
      sacc[kc] = MFMA32(kb2, bq1, sacc[kc]);
    }
    float sv[4][4];
    if (k0 + 63 > q0) {
      const int q = q0 + l15;
#pragma unroll
      for (int kc = 0; kc < 4; ++kc)
#pragma unroll
        for (int r = 0; r < 4; ++r) {
          int key = k0 + kc * 16 + 4 * g + r;
          sv[kc][r] = (key <= q) ? sacc[kc][r] * sc : -1e30f;
        }
    } else {
#pragma unroll
      for (int kc = 0; kc < 4; ++kc)
#pragma unroll
        for (int r = 0; r < 4; ++r) sv[kc][r] = sacc[kc][r] * sc;
    }
    float pm = sv[0][0];
#pragma unroll
    for (int kc = 0; kc < 4; ++kc)
#pragma unroll
      for (int r = 0; r < 4; ++r) pm = fmaxf(pm, sv[kc][r]);
    if (__any(pm > m + 8.f)) {
      pm = fmaxf(pm, __shfl_xor(pm, 16));
      pm = fmaxf(pm, __shfl_xor(pm, 32));
      float mn = fmaxf(m, pm);
      float alpha = exp2f(m - mn);
      lsum *= alpha;
      float an[4];
#pragma unroll
      for (int r = 0; r < 4; ++r) an[r] = __shfl(alpha, 4 * g + r);
#pragma unroll
      for (int hf = 0; hf < 4; ++hf)
#pragma unroll
        for (int r = 0; r < 4; ++r) o[hf][r] *= an[r];
      m = mn;
    }
    float ts = 0.f;
#pragma unroll
    for (int kc = 0; kc < 4; ++kc)
#pragma unroll
      for (int r = 0; r < 4; ++r) { sv[kc][r] = exp2f(sv[kc][r] - m); ts += sv[kc][r]; }
    ts += __shfl_xor(ts, 16);
    ts += __shfl_xor(ts, 32);
    lsum += ts;
    bf16x4 pa[4];
#pragma unroll
    for (int kc = 0; kc < 4; ++kc) {
      pa[kc][0] = (short)f2bf(sv[kc][0]); pa[kc][1] = (short)f2bf(sv[kc][1]);
      pa[kc][2] = (short)f2bf(sv[kc][2]); pa[kc][3] = (short)f2bf(sv[kc][3]);
    }
#pragma unroll
    for (int hf = 0; hf < 4; ++hf)
#pragma unroll
      for (int kc = 0; kc < 4; ++kc)
        o[hf] = MFMA16(pa[kc], vf[hf][kc], o[hf]);
  }
  const float il = 1.f / lsum;
  float iln[4];
#pragma unroll
  for (int r = 0; r < 4; ++r) iln[r] = __shfl(il, 4 * g + r);
  float* ob = out + ((size_t)b * Tn + q0) * 64;
#pragma unroll
  for (int hf = 0; hf < 4; ++hf)
#pragma unroll
    for (int r = 0; r < 4; ++r)
      ob[(size_t)(4 * g + r) * 64 + hf * 16 + l15] = o[hf][r] * iln[r];
}

// ---------------------------------------------------------------------------
extern "C" void kernel_launch(void* const* d_in, const int* in_sizes, int n_in,
                              void* d_out, int out_size, void* d_ws, size_t ws_size,
                              hipStream_t stream) {
  const float* x  = (const float*)d_in[0];
  const float* Wq = (const float*)d_in[1];
  const float* Wk = (const float*)d_in[2];
  const float* Wv = (const float*)d_in[3];
  float* out = (float*)d_out;

  // ws layout (bf16): Wt[3*64*1024] | Q | K | Vt  (each B*T*64), then fp32 partials
  unsigned short* Wt = (unsigned short*)d_ws;
  unsigned short* Qs = Wt + 3 * 64 * 1024;
  unsigned short* Ks = Qs + (size_t)Bn * Tn * Hn;
  unsigned short* Vt = Ks + (size_t)Bn * Tn * Hn;
  const size_t bf_bytes = (3 * 64 * 1024 + 3 * (size_t)Bn * Tn * Hn) * 2;
  float* po = (float*)((char*)d_ws + bf_bytes);

  const size_t nslots = (size_t)Bn * 140;   // packed partial slots
  float* pml = po + nslots * 4096;
  const size_t need = bf_bytes + nslots * (4096 + 128) * sizeof(float);  // ~25 MB

  hipLaunchKernelGGL(k_prep, dim3(192), dim3(256), 0, stream, Wq, Wk, Wv, Wt);
  hipLaunchKernelGGL(k_qkv, dim3(512), dim3(256), 0, stream, x, Wt, Qs, Ks, Vt);
  if (ws_size >= need) {
    hipLaunchKernelGGL(k_attn_coop, dim3(1152), dim3(256), 0, stream, Qs, Ks, Vt, out, po, pml);
    hipLaunchKernelGGL(k_comb, dim3(28, 8), dim3(256), 0, stream, po, pml, out);
  } else {
    hipLaunchKernelGGL(k_attn_wave, dim3(256), dim3(256), 0, stream, Qs, Ks, Vt, out);
  }
}

// Round 14
// 57.358 us; speedup vs baseline: 1.5092x; 1.5092x over previous
//
#include <hip/hip_runtime.h>
#include <hip/hip_bf16.h>
#include <stdint.h>

// Problem constants: B=8, T=2048, C=1024, H=64. Single-head causal attention.
#define Bn 8
#define Tn 2048
#define Cn 1024
#define Hn 64

typedef __attribute__((ext_vector_type(8))) short bf16x8;  // 8 bf16 (MFMA K=32 A/B frag)
typedef __attribute__((ext_vector_type(4))) short bf16x4;  // 4 bf16 (MFMA K=16 A/B frag)
typedef __attribute__((ext_vector_type(4))) float f32x4;   // MFMA C/D frag

// __has_builtin for amdgcn builtins is false in the HOST pass; device-only check.
#if defined(__HIP_DEVICE_COMPILE__) && !__has_builtin(__builtin_amdgcn_mfma_f32_16x16x16bf16_1k)
#error "mfma_f32_16x16x16bf16_1k required on gfx950"
#endif
#define MFMA16(a, b, c) __builtin_amdgcn_mfma_f32_16x16x16bf16_1k(a, b, c, 0, 0, 0)
#define MFMA32(a, b, c) __builtin_amdgcn_mfma_f32_16x16x32_bf16(a, b, c, 0, 0, 0)

__device__ __forceinline__ unsigned short f2bf(float f) {
  union { float f; unsigned int u; } v; v.f = f;
  unsigned int u = v.u;
  u = u + 0x7fffu + ((u >> 16) & 1u);   // round-nearest-even
  return (unsigned short)(u >> 16);
}

// async global(16B/lane) -> LDS (wave-uniform dest base + lane*16)
__device__ __forceinline__ void gload16(const void* g, void* l) {
  __builtin_amdgcn_global_load_lds(
      (const __attribute__((address_space(1))) unsigned int*)g,
      (__attribute__((address_space(3))) unsigned int*)l, 16, 0, 0);
}

// ---------------------------------------------------------------------------
// k_prep: Wt[m][h][c] = W_m[c][h] as bf16.  grid=192 (m*64+h), block=256.
// ---------------------------------------------------------------------------
__global__ __launch_bounds__(256) void k_prep(const float* __restrict__ Wq,
                                              const float* __restrict__ Wk,
                                              const float* __restrict__ Wv,
                                              unsigned short* __restrict__ Wt) {
  const int m = blockIdx.x >> 6;
  const int h = blockIdx.x & 63;
  const float* W = (m == 0) ? Wq : (m == 1) ? Wk : Wv;
  const int tid = threadIdx.x;
  unsigned short* dst = Wt + ((size_t)(m * 64 + h)) * 1024;
#pragma unroll
  for (int j = 0; j < 4; ++j) {
    int c = j * 256 + tid;
    dst[c] = f2bf(W[(size_t)c * 64 + h]);
  }
}

// ---------------------------------------------------------------------------
// k_qkv: C[16384x192] = x * W (Q|K|V), bf16 MFMA.
// R14 theory: the 37us invariant (R8/R9/R11/R12) = 16 serial barrier-steps
// whose per-wave compute (~500cyc at BK=64) < HBM latency (~900cyc), so
// double-buffering never hides the staging. Fix BOTH terms:
//   * BK=128 -> 8 K-steps, per-wave compute/step = 24 MFMA + cvt ~ 1500-2500
//     cyc > latency -> the 1-barrier/step dbuf can finally hide staging.
//   * 64-row x 192-col tile, grid 256 (1 block/CU), block 512 (8 waves).
// Staging: W via gload_lds (zero regs, granule-XOR swizzle, R9-proven) into
// dbuf; x reg-staged fp32->bf16 (4 float4/thread, dies within step, R5-proven)
// into the OTHER x buffer. ONE barrier per step:
//   { stage W(t+1) async; stage x(t+1); compute(t); barrier }
// LDS: xs 2x17.4KB + W 2x48KB = 130KB. Epilogue os[64][200] aliases xs.
// ---------------------------------------------------------------------------
__global__ __launch_bounds__(512, 1) void k_qkv(const float* __restrict__ x,
                                                const unsigned short* __restrict__ Wt,
                                                unsigned short* __restrict__ Q,
                                                unsigned short* __restrict__ K,
                                                unsigned short* __restrict__ Vt) {
  // layout (bytes): xs0 @0 (64x136 bf16 =17408) | xs1 @17408 | wl0 @34816
  // (192x128 bf16 =49152) | wl1 @83968.  os[64][200] aliases @0 (epilogue).
  __shared__ __align__(16) char smem[133120];

  const int tid = threadIdx.x;
  const int lane = tid & 63;
  const int wid = __builtin_amdgcn_readfirstlane(tid >> 6);  // 0..7
  const int wm = wid >> 2, wn = wid & 3;   // 2 row-groups x 4 col-groups
  const int l15 = lane & 15, g = lane >> 4;
  const int r0 = blockIdx.x * 64;

  f32x4 acc[2][3];
#pragma unroll
  for (int mf = 0; mf < 2; ++mf)
#pragma unroll
    for (int nf = 0; nf < 3; ++nf)
#pragma unroll
      for (int r = 0; r < 4; ++r) acc[mf][nf][r] = 0.f;

  // W stage: 48 chunks of 1KB (4 rows x 128 bf16); wave stages chunks
  // wid + 8j. Lane -> row cidx*4 + (lane>>4), granule lane&15; source
  // pre-swizzled so phys granule p holds logical p ^ (row&15).
  auto stageW = [&](int buf, int kt) {
    char* wl = smem + 34816 + buf * 49152;
    const int k0 = kt * 128;
#pragma unroll
    for (int j = 0; j < 6; ++j) {
      const int cidx = wid + j * 8;
      const int row = cidx * 4 + (lane >> 4);
      const int lg = (lane & 15) ^ (row & 15);
      gload16(Wt + (size_t)row * 1024 + k0 + lg * 8, wl + cidx * 1024);
    }
  };
  // x stage: 64 rows x 128 k fp32 -> bf16 into xs[buf] (padded [64][136]).
  // 512 threads: row tid>>3, 16 floats at col (tid&7)*16. Regs die at write.
  auto stageX = [&](int buf, int kt) {
    unsigned short (*xs)[136] = (unsigned short (*)[136])(smem + buf * 17408);
    const int row = tid >> 3;
    const int c0 = (tid & 7) * 16;
    const float* xp = x + (size_t)(r0 + row) * 1024 + kt * 128 + c0;
    float4 v0 = *(const float4*)xp;
    float4 v1 = *(const float4*)(xp + 4);
    float4 v2 = *(const float4*)(xp + 8);
    float4 v3 = *(const float4*)(xp + 12);
    ushort4 b0, b1, b2, b3;
    b0.x = f2bf(v0.x); b0.y = f2bf(v0.y); b0.z = f2bf(v0.z); b0.w = f2bf(v0.w);
    b1.x = f2bf(v1.x); b1.y = f2bf(v1.y); b1.z = f2bf(v1.z); b1.w = f2bf(v1.w);
    b2.x = f2bf(v2.x); b2.y = f2bf(v2.y); b2.z = f2bf(v2.z); b2.w = f2bf(v2.w);
    b3.x = f2bf(v3.x); b3.y = f2bf(v3.y); b3.z = f2bf(v3.z); b3.w = f2bf(v3.w);
    *(ushort4*)&xs[row][c0] = b0;
    *(ushort4*)&xs[row][c0 + 4] = b1;
    *(ushort4*)&xs[row][c0 + 8] = b2;
    *(ushort4*)&xs[row][c0 + 12] = b3;
  };

  stageW(0, 0);
  stageX(0, 0);
  __syncthreads();

  for (int kt = 0; kt < 8; ++kt) {
    const int cur = kt & 1;
    if (kt < 7) {
      stageW(cur ^ 1, kt + 1);       // async, lands during compute
      stageX(cur ^ 1, kt + 1);       // regs die at ds_write
    }
    const unsigned short (*xs)[136] =
        (const unsigned short (*)[136])(smem + cur * 17408);
    const unsigned short* wl = (const unsigned short*)(smem + 34816 + cur * 49152);
#pragma unroll
    for (int ks = 0; ks < 4; ++ks) {
      bf16x8 a0 = *(const bf16x8*)&xs[wm * 32 + l15][ks * 32 + g * 8];
      bf16x8 a1 = *(const bf16x8*)&xs[wm * 32 + 16 + l15][ks * 32 + g * 8];
#pragma unroll
      for (int nf = 0; nf < 3; ++nf) {
        const int row = wn * 48 + nf * 16 + l15;
        const int phys = (ks * 4 + g) ^ (row & 15);
        bf16x8 b = *(const bf16x8*)&wl[row * 128 + phys * 8];
        acc[0][nf] = MFMA32(a0, b, acc[0][nf]);
        acc[1][nf] = MFMA32(a1, b, acc[1][nf]);
      }
    }
    __syncthreads();   // drains this step's gloads + x writes; readers done
  }

  // epilogue: acc -> os (bf16). D layout: col = l15, row = 4g+r.
  unsigned short (*os)[200] = (unsigned short (*)[200])smem;
#pragma unroll
  for (int mf = 0; mf < 2; ++mf)
#pragma unroll
    for (int nf = 0; nf < 3; ++nf)
#pragma unroll
      for (int r = 0; r < 4; ++r)
        os[wm * 32 + mf * 16 + 4 * g + r][wn * 48 + nf * 16 + l15] =
            f2bf(acc[mf][nf][r]);
  __syncthreads();

  const int b = r0 >> 11;
  const int t0 = r0 & 2047;
  // Q, K: 64 rows x 8 uint4-chunks = 512 each; 1 per thread each.
  {
    int row = tid >> 3, ch = tid & 7;
    *(uint4*)(Q + (size_t)(r0 + row) * 64 + ch * 8) = *(const uint4*)&os[row][ch * 8];
    *(uint4*)(K + (size_t)(r0 + row) * 64 + ch * 8) = *(const uint4*)&os[row][64 + ch * 8];
  }
  // Vt transpose: 64 h x 64 t; each thread 8 t-values (16B store).
  {
    int h = tid >> 3, tc = (tid & 7) * 8;
    unsigned short tmp[8];
#pragma unroll
    for (int r = 0; r < 8; ++r) tmp[r] = os[tc + r][128 + h];
    *(uint4*)(Vt + ((size_t)b * 64 + h) * 2048 + t0 + tc) = *(const uint4*)tmp;
  }
}

// ---------------------------------------------------------------------------
// k_attn_coop: block-cooperative flash attention. UNCHANGED from R7-R13
// (inferred ~11us: (256,3), XCD-bijective swizzle, gload_lds dbuf staging).
// ---------------------------------------------------------------------------
__global__ __launch_bounds__(256, 3) void k_attn_coop(const unsigned short* __restrict__ Q,
                                                      const unsigned short* __restrict__ K,
                                                      const unsigned short* __restrict__ Vt,
                                                      float* __restrict__ out,
                                                      float* __restrict__ po,
                                                      float* __restrict__ pml) {
  __shared__ __align__(16) unsigned short lds[2][8192];  // [buf][K 4096sh | V 4096sh]

  const int tid = threadIdx.x;
  const int lane = tid & 63;
  const int l15 = lane & 15, g = lane >> 4;
  const int wid = __builtin_amdgcn_readfirstlane(tid >> 6);

  // ---- task decode with XCD swizzle (1152 = 8 XCD x 144 tasks/batch) ----
  const int raw = blockIdx.x;
  const int bi = (raw & 7) * 144 + (raw >> 3);
  const int b = bi / 144;
  const int id = bi - b * 144;
  int gq = 0;
#pragma unroll
  for (int t = 1; t < 8; ++t)
    if (id >= 2 * t * (t + 1)) gq = t;
  const int rem = id - 2 * gq * (gq + 1);
  const int ql = rem / (gq + 1);
  const int s = rem - ql * (gq + 1);
  const int qt = 4 * gq + ql;          // 64-row q-tile 0..31
  const int qblk = qt * 64;
  const int klo = 256 * s;
  const int khi = min(klo + 256, qblk + 64);
  const int nt = (khi - klo + 63) >> 6;
  const int q0w = qblk + wid * 16;     // this wave's q rows

  const unsigned short* Qb = Q + (size_t)b * Tn * Hn;
  const unsigned short* Kb = K + (size_t)b * Tn * Hn;
  const unsigned short* Vb = Vt + (size_t)b * Hn * Tn;

  // Q as B-operand: lane l15 = q row, k = 8g+j
  bf16x8 bq0 = *(const bf16x8*)(Qb + (size_t)(q0w + l15) * 64 + g * 8);
  bf16x8 bq1 = *(const bf16x8*)(Qb + (size_t)(q0w + l15) * 64 + 32 + g * 8);

  f32x4 o[4];
#pragma unroll
  for (int hf = 0; hf < 4; ++hf)
#pragma unroll
    for (int r = 0; r < 4; ++r) o[hf][r] = 0.f;
  float m = -1e30f, lsum = 0.f;
  const float sc = 0.03125f * 1.44269504088896f;  // C^-0.5 * log2(e)

  // stage one 64-key tile: K[64key][64d] + V[64h][64key], swizzled granules.
  auto stage = [&](int buf, int k0) {
    unsigned short* tb = &lds[buf][0];
#pragma unroll
    for (int j = 0; j < 4; ++j) {
      const int p = wid * 256 + j * 64 + lane;
      const unsigned short* src;
      if (wid < 2) {                       // K: rows = keys
        const int row = p >> 3, c = p & 7;
        src = Kb + (size_t)(k0 + row) * 64 + ((c ^ (row & 7)) * 8);
      } else {                             // V: rows = h
        const int q = p - 512;
        const int h = q >> 3, c = q & 7;
        src = Vb + (size_t)h * Tn + k0 + ((c ^ (h & 7)) * 8);
      }
      gload16(src, tb + wid * 2048 + j * 512);
    }
  };

  stage(0, klo);
  __syncthreads();

  for (int t = 0; t < nt; ++t) {
    const int cur = t & 1;
    const int k0 = klo + t * 64;
    if (t + 1 < nt) stage(cur ^ 1, klo + (t + 1) * 64);

    const unsigned short* kt = &lds[cur][0];
    const unsigned short* vt = &lds[cur][4096];

    // S^T: lane l15 = q, reg (kc, 4g+r) = key
    f32x4 sacc[4];
#pragma unroll
    for (int kc = 0; kc < 4; ++kc) {
      const int row = kc * 16 + l15;
      const int sw = row & 7;
      bf16x8 ka = *(const bf16x8*)&kt[row * 64 + ((g ^ sw) * 8)];
      bf16x8 kb2 = *(const bf16x8*)&kt[row * 64 + (((4 + g) ^ sw) * 8)];
#pragma unroll
      for (int r = 0; r < 4; ++r) sacc[kc][r] = 0.f;
      sacc[kc] = MFMA32(ka, bq0, sacc[kc]);
      sacc[kc] = MFMA32(kb2, bq1, sacc[kc]);
    }
    // scale + causal mask (key <= q); boundary tiles only (wave-uniform)
    float sv[4][4];
    if (k0 + 63 > q0w) {
      const int q = q0w + l15;
#pragma unroll
      for (int kc = 0; kc < 4; ++kc)
#pragma unroll
        for (int r = 0; r < 4; ++r) {
          int key = k0 + kc * 16 + 4 * g + r;
          sv[kc][r] = (key <= q) ? sacc[kc][r] * sc : -1e30f;
        }
    } else {
#pragma unroll
      for (int kc = 0; kc < 4; ++kc)
#pragma unroll
        for (int r = 0; r < 4; ++r) sv[kc][r] = sacc[kc][r] * sc;
    }
    // defer-max: lane-local max suffices for the trigger test
    float pm = sv[0][0];
#pragma unroll
    for (int kc = 0; kc < 4; ++kc)
#pragma unroll
      for (int r = 0; r < 4; ++r) pm = fmaxf(pm, sv[kc][r]);
    if (__any(pm > m + 8.f)) {
      pm = fmaxf(pm, __shfl_xor(pm, 16));
      pm = fmaxf(pm, __shfl_xor(pm, 32));
      float mn = fmaxf(m, pm);
      float alpha = exp2f(m - mn);
      lsum *= alpha;
      float an[4];
#pragma unroll
      for (int r = 0; r < 4; ++r) an[r] = __shfl(alpha, 4 * g + r);
#pragma unroll
      for (int hf = 0; hf < 4; ++hf)
#pragma unroll
        for (int r = 0; r < 4; ++r) o[hf][r] *= an[r];
      m = mn;
    }
    float ts = 0.f;
#pragma unroll
    for (int kc = 0; kc < 4; ++kc)
#pragma unroll
      for (int r = 0; r < 4; ++r) { sv[kc][r] = exp2f(sv[kc][r] - m); ts += sv[kc][r]; }
    ts += __shfl_xor(ts, 16);
    ts += __shfl_xor(ts, 32);
    lsum += ts;
    // P in K=16 A-operand layout: lane l15 = q, k-local = 4g+r
    bf16x4 pa[4];
#pragma unroll
    for (int kc = 0; kc < 4; ++kc) {
      pa[kc][0] = (short)f2bf(sv[kc][0]); pa[kc][1] = (short)f2bf(sv[kc][1]);
      pa[kc][2] = (short)f2bf(sv[kc][2]); pa[kc][3] = (short)f2bf(sv[kc][3]);
    }
    // V frags from LDS: B-operand lane l15 = h col, k-local = 4g+r
    bf16x4 vf[4][4];
#pragma unroll
    for (int hf = 0; hf < 4; ++hf) {
      const int h = hf * 16 + l15, hs = h & 7;
#pragma unroll
      for (int kc = 0; kc < 4; ++kc) {
        const int gran = (kc * 2 + (g >> 1)) ^ hs;
        vf[hf][kc] = *(const bf16x4*)&vt[h * 64 + gran * 8 + (g & 1) * 4];
      }
    }
#pragma unroll
    for (int hf = 0; hf < 4; ++hf)
#pragma unroll
      for (int kc = 0; kc < 4; ++kc)
        o[hf] = MFMA16(pa[kc], vf[hf][kc], o[hf]);

    __syncthreads();   // drains stage vmcnt + all waves done reading buf
  }

  if (qt >= 4) {
    // packed partial: slot = task id - 4 within batch
    const int slot = b * 140 + id - 4;
    float* pob = po + (size_t)slot * 4096;
#pragma unroll
    for (int hf = 0; hf < 4; ++hf)
#pragma unroll
      for (int r = 0; r < 4; ++r)
        pob[(16 * wid + 4 * g + r) * 64 + hf * 16 + l15] = o[hf][r];
    if (lane < 16) {
      pml[(size_t)slot * 128 + 16 * wid + l15] = m;
      pml[(size_t)slot * 128 + 64 + 16 * wid + l15] = lsum;
    }
  } else {
    const float il = 1.f / lsum;
    float iln[4];
#pragma unroll
    for (int r = 0; r < 4; ++r) iln[r] = __shfl(il, 4 * g + r);
    float* ob = out + ((size_t)b * Tn + q0w) * 64;
#pragma unroll
    for (int hf = 0; hf < 4; ++hf)
#pragma unroll
      for (int r = 0; r < 4; ++r)
        ob[(size_t)(4 * g + r) * 64 + hf * 16 + l15] = o[hf][r] * iln[r];
  }
}

// ---------------------------------------------------------------------------
// k_comb: merge 2..8 segments per (b, qt 4..31). grid=(28,8), block=256.
// ---------------------------------------------------------------------------
__global__ __launch_bounds__(256) void k_comb(const float* __restrict__ po,
                                              const float* __restrict__ pml,
                                              float* __restrict__ out) {
  const int qt = 4 + blockIdx.x;
  const int b = blockIdx.y;
  const int gq = qt >> 2, ql = qt & 3;
  const int nseg = gq + 1;
  const int base = b * 140 + 2 * gq * (gq + 1) + ql * (gq + 1) - 4;
  const int r = threadIdx.x >> 2;
  const int cg = threadIdx.x & 3;

  float mv[8], lv[8], M = -1e30f;
#pragma unroll
  for (int s = 0; s < 8; ++s)
    if (s < nseg) {
      mv[s] = pml[(size_t)(base + s) * 128 + r];
      lv[s] = pml[(size_t)(base + s) * 128 + 64 + r];
      M = fmaxf(M, mv[s]);
    }
  float w[8], L = 0.f;
#pragma unroll
  for (int s = 0; s < 8; ++s)
    if (s < nseg) { w[s] = exp2f(mv[s] - M); L += w[s] * lv[s]; }

  float acc[16];
#pragma unroll
  for (int c = 0; c < 16; ++c) acc[c] = 0.f;
#pragma unroll
  for (int s = 0; s < 8; ++s)
    if (s < nseg) {
      const float* pb = po + (size_t)(base + s) * 4096 + r * 64 + cg * 16;
#pragma unroll
      for (int j = 0; j < 4; ++j) {
        float4 v = *(const float4*)(pb + 4 * j);
        acc[4 * j + 0] += w[s] * v.x; acc[4 * j + 1] += w[s] * v.y;
        acc[4 * j + 2] += w[s] * v.z; acc[4 * j + 3] += w[s] * v.w;
      }
    }
  const float invL = 1.f / L;
  float* ob = out + ((size_t)b * Tn + qt * 64 + r) * 64 + cg * 16;
#pragma unroll
  for (int j = 0; j < 4; ++j) {
    float4 v;
    v.x = acc[4 * j + 0] * invL; v.y = acc[4 * j + 1] * invL;
    v.z = acc[4 * j + 2] * invL; v.w = acc[4 * j + 3] * invL;
    *(float4*)(ob + 4 * j) = v;
  }
}

// ---------------------------------------------------------------------------
// k_attn_wave: per-wave fallback (full key range), tiny workspace only.
// ---------------------------------------------------------------------------
__global__ __launch_bounds__(256, 2) void k_attn_wave(const unsigned short* __restrict__ Q,
                                                      const unsigned short* __restrict__ K,
                                                      const unsigned short* __restrict__ Vt,
                                                      float* __restrict__ out) {
  const int tid = threadIdx.x;
  const int lane = tid & 63;
  const int l15 = lane & 15, g = lane >> 4;
  const int wid = tid >> 6;
  const int task = blockIdx.x * 4 + wid;
  const int b = task >> 7, qt = task & 127;
  const int q0 = qt * 16;
  const int nt = (q0 + 16 + 63) >> 6;

  const unsigned short* Qb = Q + (size_t)b * Tn * Hn;
  const unsigned short* Kb = K + (size_t)b * Tn * Hn;
  const unsigned short* Vb = Vt + (size_t)b * Hn * Tn;

  bf16x8 bq0 = *(const bf16x8*)(Qb + (size_t)(q0 + l15) * 64 + g * 8);
  bf16x8 bq1 = *(const bf16x8*)(Qb + (size_t)(q0 + l15) * 64 + 32 + g * 8);

  f32x4 o[4];
#pragma unroll
  for (int hf = 0; hf < 4; ++hf)
#pragma unroll
    for (int r = 0; r < 4; ++r) o[hf][r] = 0.f;
  float m = -1e30f, lsum = 0.f;
  const float sc = 0.03125f * 1.44269504088896f;

  for (int t = 0; t < nt; ++t) {
    const int k0 = t * 64;
    bf16x4 vf[4][4];
#pragma unroll
    for (int hf = 0; hf < 4; ++hf) {
      const unsigned short* vrow = Vb + (size_t)(hf * 16 + l15) * Tn + k0 + 4 * g;
#pragma unroll
      for (int kc = 0; kc < 4; ++kc) vf[hf][kc] = *(const bf16x4*)(vrow + kc * 16);
    }
    f32x4 sacc[4];
#pragma unroll
    for (int kc = 0; kc < 4; ++kc) {
      const unsigned short* kp = Kb + (size_t)(k0 + kc * 16 + l15) * 64 + g * 8;
      bf16x8 ka = *(const bf16x8*)kp;
      bf16x8 kb2 = *(const bf16x8*)(kp + 32);
#pragma unroll
      for (int r = 0; r < 4; ++r) sacc[kc][r] = 0.f;
      sacc[kc] = MFMA32(ka, bq0, sacc[kc]);
      sacc[kc] = MFMA32(kb2, bq1, sacc[kc]);
    }
    float sv[4][4];
    if (k0 + 63 > q0) {
      const int q = q0 + l15;
#pragma unroll
      for (int kc = 0; kc < 4; ++kc)
#pragma unroll
        for (int r = 0; r < 4; ++r) {
          int key = k0 + kc * 16 + 4 * g + r;
          sv[kc][r] = (key <= q) ? sacc[kc][r] * sc : -1e30f;
        }
    } else {
#pragma unroll
      for (int kc = 0; kc < 4; ++kc)
#pragma unroll
        for (int r = 0; r < 4; ++r) sv[kc][r] = sacc[kc][r] * sc;
    }
    float pm = sv[0][0];
#pragma unroll
    for (int kc = 0; kc < 4; ++kc)
#pragma unroll
      for (int r = 0; r < 4; ++r) pm = fmaxf(pm, sv[kc][r]);
    if (__any(pm > m + 8.f)) {
      pm = fmaxf(pm, __shfl_xor(pm, 16));
      pm = fmaxf(pm, __shfl_xor(pm, 32));
      float mn = fmaxf(m, pm);
      float alpha = exp2f(m - mn);
      lsum *= alpha;
      float an[4];
#pragma unroll
      for (int r = 0; r < 4; ++r) an[r] = __shfl(alpha, 4 * g + r);
#pragma unroll
      for (int hf = 0; hf < 4; ++hf)
#pragma unroll
        for (int r = 0; r < 4; ++r) o[hf][r] *= an[r];
      m = mn;
    }
    float ts = 0.f;
#pragma unroll
    for (int kc = 0; kc < 4; ++kc)
#pragma unroll
      for (int r = 0; r < 4; ++r) { sv[kc][r] = exp2f(sv[kc][r] - m); ts += sv[kc][r]; }
    ts += __shfl_xor(ts, 16);
    ts += __shfl_xor(ts, 32);
    lsum += ts;
    bf16x4 pa[4];
#pragma unroll
    for (int kc = 0; kc < 4; ++kc) {
      pa[kc][0] = (short)f2bf(sv[kc][0]); pa[kc][1] = (short)f2bf(sv[kc][1]);
      pa[kc][2] = (short)f2bf(sv[kc][2]); pa[kc][3] = (short)f2bf(sv[kc][3]);
    }
#pragma unroll
    for (int hf = 0; hf < 4; ++hf)
#pragma unroll
      for (int kc = 0; kc < 4; ++kc)
        o[hf] = MFMA16(pa[kc], vf[hf][kc], o[hf]);
  }
  const float il = 1.f / lsum;
  float iln[4];
#pragma unroll
  for (int r = 0; r < 4; ++r) iln[r] = __shfl(il, 4 * g + r);
  float* ob = out + ((size_t)b * Tn + q0) * 64;
#pragma unroll
  for (int hf = 0; hf < 4; ++hf)
#pragma unroll
    for (int r = 0; r < 4; ++r)
      ob[(size_t)(4 * g + r) * 64 + hf * 16 + l15] = o[hf][r] * iln[r];
}

// ---------------------------------------------------------------------------
extern "C" void kernel_launch(void* const* d_in, const int* in_sizes, int n_in,
                              void* d_out, int out_size, void* d_ws, size_t ws_size,
                              hipStream_t stream) {
  const float* x  = (const float*)d_in[0];
  const float* Wq = (const float*)d_in[1];
  const float* Wk = (const float*)d_in[2];
  const float* Wv = (const float*)d_in[3];
  float* out = (float*)d_out;

  // ws layout (bf16): Wt[3*64*1024] | Q | K | Vt  (each B*T*64), then fp32 partials
  unsigned short* Wt = (unsigned short*)d_ws;
  unsigned short* Qs = Wt + 3 * 64 * 1024;
  unsigned short* Ks = Qs + (size_t)Bn * Tn * Hn;
  unsigned short* Vt = Ks + (size_t)Bn * Tn * Hn;
  const size_t bf_bytes = (3 * 64 * 1024 + 3 * (size_t)Bn * Tn * Hn) * 2;
  float* po = (float*)((char*)d_ws + bf_bytes);

  const size_t nslots = (size_t)Bn * 140;   // packed partial slots
  float* pml = po + nslots * 4096;
  const size_t need = bf_bytes + nslots * (4096 + 128) * sizeof(float);  // ~25 MB

  hipLaunchKernelGGL(k_prep, dim3(192), dim3(256), 0, stream, Wq, Wk, Wv, Wt);
  hipLaunchKernelGGL(k_qkv, dim3(256), dim3(512), 0, stream, x, Wt, Qs, Ks, Vt);
  if (ws_size >= need) {
    hipLaunchKernelGGL(k_attn_coop, dim3(1152), dim3(256), 0, stream, Qs, Ks, Vt, out, po, pml);
    hipLaunchKernelGGL(k_comb, dim3(28, 8), dim3(256), 0, stream, po, pml, out);
  } else {
    hipLaunchKernelGGL(k_attn_wave, dim3(256), dim3(256), 0, stream, Qs, Ks, Vt, out);
  }
}

// Round 15
// 52.898 us; speedup vs baseline: 1.6365x; 1.0843x over previous
//
#include <hip/hip_runtime.h>
#include <hip/hip_bf16.h>
#include <stdint.h>

// Problem constants: B=8, T=2048, C=1024, H=64. Single-head causal attention.
#define Bn 8
#define Tn 2048
#define Cn 1024
#define Hn 64

typedef __attribute__((ext_vector_type(8))) short bf16x8;  // 8 bf16 (MFMA K=32 A/B frag)
typedef __attribute__((ext_vector_type(4))) short bf16x4;  // 4 bf16 (MFMA K=16 A/B frag)
typedef __attribute__((ext_vector_type(4))) float f32x4;   // MFMA C/D frag

// __has_builtin for amdgcn builtins is false in the HOST pass; device-only check.
#if defined(__HIP_DEVICE_COMPILE__) && !__has_builtin(__builtin_amdgcn_mfma_f32_16x16x16bf16_1k)
#error "mfma_f32_16x16x16bf16_1k required on gfx950"
#endif
#define MFMA16(a, b, c) __builtin_amdgcn_mfma_f32_16x16x16bf16_1k(a, b, c, 0, 0, 0)
#define MFMA32(a, b, c) __builtin_amdgcn_mfma_f32_16x16x32_bf16(a, b, c, 0, 0, 0)

__device__ __forceinline__ unsigned short f2bf(float f) {
  union { float f; unsigned int u; } v; v.f = f;
  unsigned int u = v.u;
  u = u + 0x7fffu + ((u >> 16) & 1u);   // round-nearest-even
  return (unsigned short)(u >> 16);
}

// async global(16B/lane) -> LDS (wave-uniform dest base + lane*16)
__device__ __forceinline__ void gload16(const void* g, void* l) {
  __builtin_amdgcn_global_load_lds(
      (const __attribute__((address_space(1))) unsigned int*)g,
      (__attribute__((address_space(3))) unsigned int*)l, 16, 0, 0);
}

// ---------------------------------------------------------------------------
// k_prep: Wt[m][h][c] = W_m[c][h] as bf16.  grid=192 (m*64+h), block=256.
// ---------------------------------------------------------------------------
__global__ __launch_bounds__(256) void k_prep(const float* __restrict__ Wq,
                                              const float* __restrict__ Wk,
                                              const float* __restrict__ Wv,
                                              unsigned short* __restrict__ Wt) {
  const int m = blockIdx.x >> 6;
  const int h = blockIdx.x & 63;
  const float* W = (m == 0) ? Wq : (m == 1) ? Wk : Wv;
  const int tid = threadIdx.x;
  unsigned short* dst = Wt + ((size_t)(m * 64 + h)) * 1024;
#pragma unroll
  for (int j = 0; j < 4; ++j) {
    int c = j * 256 + tid;
    dst[c] = f2bf(W[(size_t)c * 64 + h]);
  }
}

// ---------------------------------------------------------------------------
// k_qkv COUNTED-VMCNT PIPELINE: C[16384x192] = x * W, bf16 MFMA.
// R14 finding (guide §5 m97-ceiling): __syncthreads drains vmcnt(0) -> every
// "double-buffered" variant (R9/R12/R14) waited for the NEXT tile's loads at
// each barrier; prefetch structurally nullified -> 37-41us invariant.
// Fix = T4: raw s_barrier + counted `s_waitcnt vmcnt(5)` so stage(t+2)'s
// loads stay IN FLIGHT across the barrier. Triple buffer (40KB x3 = 120KB)
// makes early issue race-free: stage writes buf[(t+2)%3]; concurrent readers
// on buf[t%3]. All staging via gload_lds (zero regs): x as RAW FP32
// (cvt at frag build, R9-proven granule-XOR maps), W bf16. 5 loads/wave/step.
// 64-row x 192-col tiles, grid 256, block 512 (8 waves: 2 rowg x 4 colg).
// ---------------------------------------------------------------------------
__global__ __launch_bounds__(512, 1) void k_qkv(const float* __restrict__ x,
                                                const unsigned short* __restrict__ Wt,
                                                unsigned short* __restrict__ Q,
                                                unsigned short* __restrict__ K,
                                                unsigned short* __restrict__ Vt) {
  // buf b at smem + b*40960: x fp32 [64][64] (16KB) | W bf16 [192][64] (24KB).
  // os[64][200] aliases buf0 after the final loop barrier.
  __shared__ __align__(16) char smem[122880];

  const int tid = threadIdx.x;
  const int lane = tid & 63;
  const int wid = __builtin_amdgcn_readfirstlane(tid >> 6);  // 0..7
  const int wm = wid >> 2, wn = wid & 3;
  const int l15 = lane & 15, g = lane >> 4;
  const int r0 = blockIdx.x * 64;

  f32x4 acc[2][3];
#pragma unroll
  for (int mf = 0; mf < 2; ++mf)
#pragma unroll
    for (int nf = 0; nf < 3; ++nf)
#pragma unroll
      for (int r = 0; r < 4; ++r) acc[mf][nf][r] = 0.f;

  // stage one K-step into buf: x 16 chunks (4 rows x 64 fp32 = 1KB) + W 24
  // chunks (8 rows x 64 bf16 = 1KB). 5 gload_lds per wave. Source granules
  // pre-swizzled: phys p holds logical p^(row&7)  (R9-refcheck'd maps).
  auto stage = [&](int buf, int kt) {
    char* base = smem + buf * 40960;
    const int k0 = kt * 64;
#pragma unroll
    for (int j = 0; j < 2; ++j) {                    // x chunks wid*2+j
      const int c = wid * 2 + j;
      const int row = c * 4 + (lane >> 4);
      const int lg = (lane & 15) ^ (row & 7);
      gload16(x + (size_t)(r0 + row) * 1024 + k0 + lg * 4, base + c * 1024);
    }
#pragma unroll
    for (int j = 0; j < 3; ++j) {                    // W chunks wid*3+j
      const int cw = wid * 3 + j;
      const int row = cw * 8 + (lane >> 3);
      const int lg = (lane & 7) ^ (row & 7);
      gload16(Wt + (size_t)row * 1024 + k0 + lg * 8, base + 16384 + cw * 1024);
    }
  };

  stage(0, 0);
  stage(1, 1);                     // 10 outstanding / wave
  __builtin_amdgcn_sched_barrier(0);
  asm volatile("s_waitcnt vmcnt(5)" ::: "memory");   // stage(0) landed
  __builtin_amdgcn_sched_barrier(0);
  __builtin_amdgcn_s_barrier();    // all waves' stage(0) landed

  const int myrow = wm * 32 + l15;
  const int rs = myrow & 7;        // (myrow+16)&7 == rs too
  for (int kt = 0; kt < 16; ++kt) {
    // issue stage(t+2) EARLY: flies under compute AND across the barrier
    if (kt + 2 <= 15) stage((kt + 2) % 3, kt + 2);
    const char* base = smem + (kt % 3) * 40960;
    const float* xf = (const float*)base;            // [64][64] fp32 swizzled
    const unsigned short* wf = (const unsigned short*)(base + 16384);
#pragma unroll
    for (int kf = 0; kf < 2; ++kf) {
      f32x4 x00 = *(const f32x4*)&xf[myrow * 64 + (((kf * 8 + 2 * g) ^ rs) * 4)];
      f32x4 x01 = *(const f32x4*)&xf[myrow * 64 + (((kf * 8 + 2 * g + 1) ^ rs) * 4)];
      f32x4 x10 = *(const f32x4*)&xf[(myrow + 16) * 64 + (((kf * 8 + 2 * g) ^ rs) * 4)];
      f32x4 x11 = *(const f32x4*)&xf[(myrow + 16) * 64 + (((kf * 8 + 2 * g + 1) ^ rs) * 4)];
      bf16x8 a0, a1;
      a0[0] = (short)f2bf(x00[0]); a0[1] = (short)f2bf(x00[1]);
      a0[2] = (short)f2bf(x00[2]); a0[3] = (short)f2bf(x00[3]);
      a0[4] = (short)f2bf(x01[0]); a0[5] = (short)f2bf(x01[1]);
      a0[6] = (short)f2bf(x01[2]); a0[7] = (short)f2bf(x01[3]);
      a1[0] = (short)f2bf(x10[0]); a1[1] = (short)f2bf(x10[1]);
      a1[2] = (short)f2bf(x10[2]); a1[3] = (short)f2bf(x10[3]);
      a1[4] = (short)f2bf(x11[0]); a1[5] = (short)f2bf(x11[1]);
      a1[6] = (short)f2bf(x11[2]); a1[7] = (short)f2bf(x11[3]);
#pragma unroll
      for (int nf = 0; nf < 3; ++nf) {
        const int row = wn * 48 + nf * 16 + l15;
        bf16x8 b = *(const bf16x8*)&wf[row * 64 + (((kf * 4 + g) ^ (row & 7)) * 8)];
        acc[0][nf] = MFMA32(a0, b, acc[0][nf]);
        acc[1][nf] = MFMA32(a1, b, acc[1][nf]);
      }
    }
    // counted wait: stage(t+1) done; stage(t+2)'s 5 loads stay in flight.
    __builtin_amdgcn_sched_barrier(0);
    if (kt + 2 <= 15)
      asm volatile("s_waitcnt vmcnt(5) lgkmcnt(0)" ::: "memory");
    else
      asm volatile("s_waitcnt vmcnt(0) lgkmcnt(0)" ::: "memory");
    __builtin_amdgcn_sched_barrier(0);
    __builtin_amdgcn_s_barrier();
  }

  // epilogue: acc -> os (bf16). D layout: col=l15, row=4g+r. os aliases buf0;
  // final loop barrier ensures all compute done.
  unsigned short (*os)[200] = (unsigned short (*)[200])smem;
#pragma unroll
  for (int mf = 0; mf < 2; ++mf)
#pragma unroll
    for (int nf = 0; nf < 3; ++nf)
#pragma unroll
      for (int r = 0; r < 4; ++r)
        os[wm * 32 + mf * 16 + 4 * g + r][wn * 48 + nf * 16 + l15] =
            f2bf(acc[mf][nf][r]);
  __syncthreads();

  const int b = r0 >> 11;
  const int t0 = r0 & 2047;
  // Q, K: 64 rows x 8 uint4-chunks = 512 each; 1 per thread each.
  {
    int row = tid >> 3, ch = tid & 7;
    *(uint4*)(Q + (size_t)(r0 + row) * 64 + ch * 8) = *(const uint4*)&os[row][ch * 8];
    *(uint4*)(K + (size_t)(r0 + row) * 64 + ch * 8) = *(const uint4*)&os[row][64 + ch * 8];
  }
  // Vt transpose: 64 h x 64 t; each thread 8 t-values (16B store).
  {
    int h = tid >> 3, tc = (tid & 7) * 8;
    unsigned short tmp[8];
#pragma unroll
    for (int r = 0; r < 8; ++r) tmp[r] = os[tc + r][128 + h];
    *(uint4*)(Vt + ((size_t)b * 64 + h) * 2048 + t0 + tc) = *(const uint4*)tmp;
  }
}

// ---------------------------------------------------------------------------
// k_attn_coop: block-cooperative flash attention. UNCHANGED from R7-R14
// (inferred ~11us: (256,3), XCD-bijective swizzle, gload_lds dbuf staging).
// ---------------------------------------------------------------------------
__global__ __launch_bounds__(256, 3) void k_attn_coop(const unsigned short* __restrict__ Q,
                                                      const unsigned short* __restrict__ K,
                                                      const unsigned short* __restrict__ Vt,
                                                      float* __restrict__ out,
                                                      float* __restrict__ po,
                                                      float* __restrict__ pml) {
  __shared__ __align__(16) unsigned short lds[2][8192];  // [buf][K 4096sh | V 4096sh]

  const int tid = threadIdx.x;
  const int lane = tid & 63;
  const int l15 = lane & 15, g = lane >> 4;
  const int wid = __builtin_amdgcn_readfirstlane(tid >> 6);

  // ---- task decode with XCD swizzle (1152 = 8 XCD x 144 tasks/batch) ----
  const int raw = blockIdx.x;
  const int bi = (raw & 7) * 144 + (raw >> 3);
  const int b = bi / 144;
  const int id = bi - b * 144;
  int gq = 0;
#pragma unroll
  for (int t = 1; t < 8; ++t)
    if (id >= 2 * t * (t + 1)) gq = t;
  const int rem = id - 2 * gq * (gq + 1);
  const int ql = rem / (gq + 1);
  const int s = rem - ql * (gq + 1);
  const int qt = 4 * gq + ql;          // 64-row q-tile 0..31
  const int qblk = qt * 64;
  const int klo = 256 * s;
  const int khi = min(klo + 256, qblk + 64);
  const int nt = (khi - klo + 63) >> 6;
  const int q0w = qblk + wid * 16;     // this wave's q rows

  const unsigned short* Qb = Q + (size_t)b * Tn * Hn;
  const unsigned short* Kb = K + (size_t)b * Tn * Hn;
  const unsigned short* Vb = Vt + (size_t)b * Hn * Tn;

  // Q as B-operand: lane l15 = q row, k = 8g+j
  bf16x8 bq0 = *(const bf16x8*)(Qb + (size_t)(q0w + l15) * 64 + g * 8);
  bf16x8 bq1 = *(const bf16x8*)(Qb + (size_t)(q0w + l15) * 64 + 32 + g * 8);

  f32x4 o[4];
#pragma unroll
  for (int hf = 0; hf < 4; ++hf)
#pragma unroll
    for (int r = 0; r < 4; ++r) o[hf][r] = 0.f;
  float m = -1e30f, lsum = 0.f;
  const float sc = 0.03125f * 1.44269504088896f;  // C^-0.5 * log2(e)

  // stage one 64-key tile: K[64key][64d] + V[64h][64key], swizzled granules.
  auto stage = [&](int buf, int k0) {
    unsigned short* tb = &lds[buf][0];
#pragma unroll
    for (int j = 0; j < 4; ++j) {
      const int p = wid * 256 + j * 64 + lane;
      const unsigned short* src;
      if (wid < 2) {                       // K: rows = keys
        const int row = p >> 3, c = p & 7;
        src = Kb + (size_t)(k0 + row) * 64 + ((c ^ (row & 7)) * 8);
      } else {                             // V: rows = h
        const int q = p - 512;
        const int h = q >> 3, c = q & 7;
        src = Vb + (size_t)h * Tn + k0 + ((c ^ (h & 7)) * 8);
      }
      gload16(src, tb + wid * 2048 + j * 512);
    }
  };

  stage(0, klo);
  __syncthreads();

  for (int t = 0; t < nt; ++t) {
    const int cur = t & 1;
    const int k0 = klo + t * 64;
    if (t + 1 < nt) stage(cur ^ 1, klo + (t + 1) * 64);

    const unsigned short* kt = &lds[cur][0];
    const unsigned short* vt = &lds[cur][4096];

    // S^T: lane l15 = q, reg (kc, 4g+r) = key
    f32x4 sacc[4];
#pragma unroll
    for (int kc = 0; kc < 4; ++kc) {
      const int row = kc * 16 + l15;
      const int sw = row & 7;
      bf16x8 ka = *(const bf16x8*)&kt[row * 64 + ((g ^ sw) * 8)];
      bf16x8 kb2 = *(const bf16x8*)&kt[row * 64 + (((4 + g) ^ sw) * 8)];
#pragma unroll
      for (int r = 0; r < 4; ++r) sacc[kc][r] = 0.f;
      sacc[kc] = MFMA32(ka, bq0, sacc[kc]);
      sacc[kc] = MFMA32(kb2, bq1, sacc[kc]);
    }
    // scale + causal mask (key <= q); boundary tiles only (wave-uniform)
    float sv[4][4];
    if (k0 + 63 > q0w) {
      const int q = q0w + l15;
#pragma unroll
      for (int kc = 0; kc < 4; ++kc)
#pragma unroll
        for (int r = 0; r < 4; ++r) {
          int key = k0 + kc * 16 + 4 * g + r;
          sv[kc][r] = (key <= q) ? sacc[kc][r] * sc : -1e30f;
        }
    } else {
#pragma unroll
      for (int kc = 0; kc < 4; ++kc)
#pragma unroll
        for (int r = 0; r < 4; ++r) sv[kc][r] = sacc[kc][r] * sc;
    }
    // defer-max: lane-local max suffices for the trigger test
    float pm = sv[0][0];
#pragma unroll
    for (int kc = 0; kc < 4; ++kc)
#pragma unroll
      for (int r = 0; r < 4; ++r) pm = fmaxf(pm, sv[kc][r]);
    if (__any(pm > m + 8.f)) {
      pm = fmaxf(pm, __shfl_xor(pm, 16));
      pm = fmaxf(pm, __shfl_xor(pm, 32));
      float mn = fmaxf(m, pm);
      float alpha = exp2f(m - mn);
      lsum *= alpha;
      float an[4];
#pragma unroll
      for (int r = 0; r < 4; ++r) an[r] = __shfl(alpha, 4 * g + r);
#pragma unroll
      for (int hf = 0; hf < 4; ++hf)
#pragma unroll
        for (int r = 0; r < 4; ++r) o[hf][r] *= an[r];
      m = mn;
    }
    float ts = 0.f;
#pragma unroll
    for (int kc = 0; kc < 4; ++kc)
#pragma unroll
      for (int r = 0; r < 4; ++r) { sv[kc][r] = exp2f(sv[kc][r] - m); ts += sv[kc][r]; }
    ts += __shfl_xor(ts, 16);
    ts += __shfl_xor(ts, 32);
    lsum += ts;
    // P in K=16 A-operand layout: lane l15 = q, k-local = 4g+r
    bf16x4 pa[4];
#pragma unroll
    for (int kc = 0; kc < 4; ++kc) {
      pa[kc][0] = (short)f2bf(sv[kc][0]); pa[kc][1] = (short)f2bf(sv[kc][1]);
      pa[kc][2] = (short)f2bf(sv[kc][2]); pa[kc][3] = (short)f2bf(sv[kc][3]);
    }
    // V frags from LDS: B-operand lane l15 = h col, k-local = 4g+r
    bf16x4 vf[4][4];
#pragma unroll
    for (int hf = 0; hf < 4; ++hf) {
      const int h = hf * 16 + l15, hs = h & 7;
#pragma unroll
      for (int kc = 0; kc < 4; ++kc) {
        const int gran = (kc * 2 + (g >> 1)) ^ hs;
        vf[hf][kc] = *(const bf16x4*)&vt[h * 64 + gran * 8 + (g & 1) * 4];
      }
    }
#pragma unroll
    for (int hf = 0; hf < 4; ++hf)
#pragma unroll
      for (int kc = 0; kc < 4; ++kc)
        o[hf] = MFMA16(pa[kc], vf[hf][kc], o[hf]);

    __syncthreads();   // drains stage vmcnt + all waves done reading buf
  }

  if (qt >= 4) {
    // packed partial: slot = task id - 4 within batch
    const int slot = b * 140 + id - 4;
    float* pob = po + (size_t)slot * 4096;
#pragma unroll
    for (int hf = 0; hf < 4; ++hf)
#pragma unroll
      for (int r = 0; r < 4; ++r)
        pob[(16 * wid + 4 * g + r) * 64 + hf * 16 + l15] = o[hf][r];
    if (lane < 16) {
      pml[(size_t)slot * 128 + 16 * wid + l15] = m;
      pml[(size_t)slot * 128 + 64 + 16 * wid + l15] = lsum;
    }
  } else {
    const float il = 1.f / lsum;
    float iln[4];
#pragma unroll
    for (int r = 0; r < 4; ++r) iln[r] = __shfl(il, 4 * g + r);
    float* ob = out + ((size_t)b * Tn + q0w) * 64;
#pragma unroll
    for (int hf = 0; hf < 4; ++hf)
#pragma unroll
      for (int r = 0; r < 4; ++r)
        ob[(size_t)(4 * g + r) * 64 + hf * 16 + l15] = o[hf][r] * iln[r];
  }
}

// ---------------------------------------------------------------------------
// k_comb: merge 2..8 segments per (b, qt 4..31). grid=(28,8), block=256.
// ---------------------------------------------------------------------------
__global__ __launch_bounds__(256) void k_comb(const float* __restrict__ po,
                                              const float* __restrict__ pml,
                                              float* __restrict__ out) {
  const int qt = 4 + blockIdx.x;
  const int b = blockIdx.y;
  const int gq = qt >> 2, ql = qt & 3;
  const int nseg = gq + 1;
  const int base = b * 140 + 2 * gq * (gq + 1) + ql * (gq + 1) - 4;
  const int r = threadIdx.x >> 2;
  const int cg = threadIdx.x & 3;

  float mv[8], lv[8], M = -1e30f;
#pragma unroll
  for (int s = 0; s < 8; ++s)
    if (s < nseg) {
      mv[s] = pml[(size_t)(base + s) * 128 + r];
      lv[s] = pml[(size_t)(base + s) * 128 + 64 + r];
      M = fmaxf(M, mv[s]);
    }
  float w[8], L = 0.f;
#pragma unroll
  for (int s = 0; s < 8; ++s)
    if (s < nseg) { w[s] = exp2f(mv[s] - M); L += w[s] * lv[s]; }

  float acc[16];
#pragma unroll
  for (int c = 0; c < 16; ++c) acc[c] = 0.f;
#pragma unroll
  for (int s = 0; s < 8; ++s)
    if (s < nseg) {
      const float* pb = po + (size_t)(base + s) * 4096 + r * 64 + cg * 16;
#pragma unroll
      for (int j = 0; j < 4; ++j) {
        float4 v = *(const float4*)(pb + 4 * j);
        acc[4 * j + 0] += w[s] * v.x; acc[4 * j + 1] += w[s] * v.y;
        acc[4 * j + 2] += w[s] * v.z; acc[4 * j + 3] += w[s] * v.w;
      }
    }
  const float invL = 1.f / L;
  float* ob = out + ((size_t)b * Tn + qt * 64 + r) * 64 + cg * 16;
#pragma unroll
  for (int j = 0; j < 4; ++j) {
    float4 v;
    v.x = acc[4 * j + 0] * invL; v.y = acc[4 * j + 1] * invL;
    v.z = acc[4 * j + 2] * invL; v.w = acc[4 * j + 3] * invL;
    *(float4*)(ob + 4 * j) = v;
  }
}

// ---------------------------------------------------------------------------
// k_attn_wave: per-wave fallback (full key range), tiny workspace only.
// ---------------------------------------------------------------------------
__global__ __launch_bounds__(256, 2) void k_attn_wave(const unsigned short* __restrict__ Q,
                                                      const unsigned short* __restrict__ K,
                                                      const unsigned short* __restrict__ Vt,
                                                      float* __restrict__ out) {
  const int tid = threadIdx.x;
  const int lane = tid & 63;
  const int l15 = lane & 15, g = lane >> 4;
  const int wid = tid >> 6;
  const int task = blockIdx.x * 4 + wid;
  const int b = task >> 7, qt = task & 127;
  const int q0 = qt * 16;
  const int nt = (q0 + 16 + 63) >> 6;

  const unsigned short* Qb = Q + (size_t)b * Tn * Hn;
  const unsigned short* Kb = K + (size_t)b * Tn * Hn;
  const unsigned short* Vb = Vt + (size_t)b * Hn * Tn;

  bf16x8 bq0 = *(const bf16x8*)(Qb + (size_t)(q0 + l15) * 64 + g * 8);
  bf16x8 bq1 = *(const bf16x8*)(Qb + (size_t)(q0 + l15) * 64 + 32 + g * 8);

  f32x4 o[4];
#pragma unroll
  for (int hf = 0; hf < 4; ++hf)
#pragma unroll
    for (int r = 0; r < 4; ++r) o[hf][r] = 0.f;
  float m = -1e30f, lsum = 0.f;
  const float sc = 0.03125f * 1.44269504088896f;

  for (int t = 0; t < nt; ++t) {
    const int k0 = t * 64;
    bf16x4 vf[4][4];
#pragma unroll
    for (int hf = 0; hf < 4; ++hf) {
      const unsigned short* vrow = Vb + (size_t)(hf * 16 + l15) * Tn + k0 + 4 * g;
#pragma unroll
      for (int kc = 0; kc < 4; ++kc) vf[hf][kc] = *(const bf16x4*)(vrow + kc * 16);
    }
    f32x4 sacc[4];
#pragma unroll
    for (int kc = 0; kc < 4; ++kc) {
      const unsigned short* kp = Kb + (size_t)(k0 + kc * 16 + l15) * 64 + g * 8;
      bf16x8 ka = *(const bf16x8*)kp;
      bf16x8 kb2 = *(const bf16x8*)(kp + 32);
#pragma unroll
      for (int r = 0; r < 4; ++r) sacc[kc][r] = 0.f;
      sacc[kc] = MFMA32(ka, bq0, sacc[kc]);
      sacc[kc] = MFMA32(kb2, bq1, sacc[kc]);
    }
    float sv[4][4];
    if (k0 + 63 > q0) {
      const int q = q0 + l15;
#pragma unroll
      for (int kc = 0; kc < 4; ++kc)
#pragma unroll
        for (int r = 0; r < 4; ++r) {
          int key = k0 + kc * 16 + 4 * g + r;
          sv[kc][r] = (key <= q) ? sacc[kc][r] * sc : -1e30f;
        }
    } else {
#pragma unroll
      for (int kc = 0; kc < 4; ++kc)
#pragma unroll
        for (int r = 0; r < 4; ++r) sv[kc][r] = sacc[kc][r] * sc;
    }
    float pm = sv[0][0];
#pragma unroll
    for (int kc = 0; kc < 4; ++kc)
#pragma unroll
      for (int r = 0; r < 4; ++r) pm = fmaxf(pm, sv[kc][r]);
    if (__any(pm > m + 8.f)) {
      pm = fmaxf(pm, __shfl_xor(pm, 16));
      pm = fmaxf(pm, __shfl_xor(pm, 32));
      float mn = fmaxf(m, pm);
      float alpha = exp2f(m - mn);
      lsum *= alpha;
      float an[4];
#pragma unroll
      for (int r = 0; r < 4; ++r) an[r] = __shfl(alpha, 4 * g + r);
#pragma unroll
      for (int hf = 0; hf < 4; ++hf)
#pragma unroll
        for (int r = 0; r < 4; ++r) o[hf][r] *= an[r];
      m = mn;
    }
    float ts = 0.f;
#pragma unroll
    for (int kc = 0; kc < 4; ++kc)
#pragma unroll
      for (int r = 0; r < 4; ++r) { sv[kc][r] = exp2f(sv[kc][r] - m); ts += sv[kc][r]; }
    ts += __shfl_xor(ts, 16);
    ts += __shfl_xor(ts, 32);
    lsum += ts;
    bf16x4 pa[4];
#pragma unroll
    for (int kc = 0; kc < 4; ++kc) {
      pa[kc][0] = (short)f2bf(sv[kc][0]); pa[kc][1] = (short)f2bf(sv[kc][1]);
      pa[kc][2] = (short)f2bf(sv[kc][2]); pa[kc][3] = (short)f2bf(sv[kc][3]);
    }
#pragma unroll
    for (int hf = 0; hf < 4; ++hf)
#pragma unroll
      for (int kc = 0; kc < 4; ++kc)
        o[hf] = MFMA16(pa[kc], vf[hf][kc], o[hf]);
  }
  const float il = 1.f / lsum;
  float iln[4];
#pragma unroll
  for (int r = 0; r < 4; ++r) iln[r] = __shfl(il, 4 * g + r);
  float* ob = out + ((size_t)b * Tn + q0) * 64;
#pragma unroll
  for (int hf = 0; hf < 4; ++hf)
#pragma unroll
    for (int r = 0; r < 4; ++r)
      ob[(size_t)(4 * g + r) * 64 + hf * 16 + l15] = o[hf][r] * iln[r];
}

// ---------------------------------------------------------------------------
extern "C" void kernel_launch(void* const* d_in, const int* in_sizes, int n_in,
                              void* d_out, int out_size, void* d_ws, size_t ws_size,
                              hipStream_t stream) {
  const float* x  = (const float*)d_in[0];
  const float* Wq = (const float*)d_in[1];
  const float* Wk = (const float*)d_in[2];
  const float* Wv = (const float*)d_in[3];
  float* out = (float*)d_out;

  // ws layout (bf16): Wt[3*64*1024] | Q | K | Vt  (each B*T*64), then fp32 partials
  unsigned short* Wt = (unsigned short*)d_ws;
  unsigned short* Qs = Wt + 3 * 64 * 1024;
  unsigned short* Ks = Qs + (size_t)Bn * Tn * Hn;
  unsigned short* Vt = Ks + (size_t)Bn * Tn * Hn;
  const size_t bf_bytes = (3 * 64 * 1024 + 3 * (size_t)Bn * Tn * Hn) * 2;
  float* po = (float*)((char*)d_ws + bf_bytes);

  const size_t nslots = (size_t)Bn * 140;   // packed partial slots
  float* pml = po + nslots * 4096;
  const size_t need = bf_bytes + nslots * (4096 + 128) * sizeof(float);  // ~25 MB

  hipLaunchKernelGGL(k_prep, dim3(192), dim3(256), 0, stream, Wq, Wk, Wv, Wt);
  hipLaunchKernelGGL(k_qkv, dim3(256), dim3(512), 0, stream, x, Wt, Qs, Ks, Vt);
  if (ws_size >= need) {
    hipLaunchKernelGGL(k_attn_coop, dim3(1152), dim3(256), 0, stream, Qs, Ks, Vt, out, po, pml);
    hipLaunchKernelGGL(k_comb, dim3(28, 8), dim3(256), 0, stream, po, pml, out);
  } else {
    hipLaunchKernelGGL(k_attn_wave, dim3(256), dim3(256), 0, stream, Qs, Ks, Vt, out);
  }
}